// Round 1
// baseline (25.148 us; speedup 1.0000x reference)
//
#include <hip/hip_runtime.h>

#define BQ  8     // batch of queries
#define DIM 128   // embedding dim

// One 32-lane group per candidate entity; lane holds float4 of 4 dims.
// 256 threads/block = 8 groups = 8 entities per block-iteration.
__global__ __launch_bounds__(256) void transe_score_kernel(
    const int*   __restrict__ head,
    const int*   __restrict__ relation,
    const int*   __restrict__ tail,
    const float* __restrict__ emb_entity,
    const float* __restrict__ emb_relation,
    const float* __restrict__ bias_head,
    const float* __restrict__ bias_tail,
    float*       __restrict__ out,
    int E)
{
    __shared__ float pred[BQ][DIM];
    __shared__ float bh_s[BQ];

    const int t = threadIdx.x;

    // pred[b][d] = emb_entity[head[b]][d] + emb_relation[relation[b]][d]
    for (int i = t; i < BQ * DIM; i += 256) {
        int b = i >> 7;       // / 128
        int d = i & 127;      // % 128
        size_t hrow = (size_t)head[b] * DIM;
        size_t rrow = (size_t)relation[b] * DIM;
        pred[b][d] = emb_entity[hrow + d] + emb_relation[rrow + d];
    }
    if (t < BQ) bh_s[t] = bias_head[head[t]];
    __syncthreads();

    const int lane = t & 31;   // lane within 32-lane entity group
    const int grp  = t >> 5;   // entity slot within block (0..7)

    // Hoist pred fragments to registers: p[b] = pred[b][4*lane .. 4*lane+3]
    float4 p[BQ];
    #pragma unroll
    for (int b = 0; b < BQ; ++b)
        p[b] = *reinterpret_cast<const float4*>(&pred[b][lane << 2]);
    float bh[BQ];
    #pragma unroll
    for (int b = 0; b < BQ; ++b) bh[b] = bh_s[b];

    const int estride = gridDim.x * 8;
    for (int e = blockIdx.x * 8 + grp; e < E; e += estride) {
        int   te = tail[e];
        float bt = bias_tail[te];
        float4 tv = *reinterpret_cast<const float4*>(
            &emb_entity[(size_t)te * DIM + (lane << 2)]);

        float acc[BQ];
        #pragma unroll
        for (int b = 0; b < BQ; ++b) {
            float dx = tv.x - p[b].x;
            float dy = tv.y - p[b].y;
            float dz = tv.z - p[b].z;
            float dw = tv.w - p[b].w;
            acc[b] = dx*dx + dy*dy + dz*dz + dw*dw;
        }

        // Selection-reduce 8 accs across 32 lanes (9 shuffles).
        // Invariant after step C: acc[0] at lane L represents b = (L>>2)&7.
        {   // mask 16: 8 -> 4 accs
            bool hi = (lane & 16) != 0;
            #pragma unroll
            for (int i = 0; i < 4; ++i) {
                float send = hi ? acc[i]     : acc[i + 4];
                float keep = hi ? acc[i + 4] : acc[i];
                acc[i] = keep + __shfl_xor(send, 16, 32);
            }
        }
        {   // mask 8: 4 -> 2 accs
            bool hi = (lane & 8) != 0;
            #pragma unroll
            for (int i = 0; i < 2; ++i) {
                float send = hi ? acc[i]     : acc[i + 2];
                float keep = hi ? acc[i + 2] : acc[i];
                acc[i] = keep + __shfl_xor(send, 8, 32);
            }
        }
        {   // mask 4: 2 -> 1 acc
            bool hi = (lane & 4) != 0;
            float send = hi ? acc[0] : acc[1];
            float keep = hi ? acc[1] : acc[0];
            acc[0] = keep + __shfl_xor(send, 4, 32);
        }
        // finish the remaining 4 lanes sharing the same b
        acc[0] += __shfl_xor(acc[0], 2, 32);
        acc[0] += __shfl_xor(acc[0], 1, 32);

        if ((lane & 3) == 0) {
            int b = lane >> 2;  // = (L>>2)&7 for L = 0,4,...,28
            out[(size_t)b * E + e] = sqrtf(acc[0]) + bh[b] + bt;
        }
    }
}

extern "C" void kernel_launch(void* const* d_in, const int* in_sizes, int n_in,
                              void* d_out, int out_size, void* d_ws, size_t ws_size,
                              hipStream_t stream) {
    const int*   head         = (const int*)  d_in[0];
    const int*   relation     = (const int*)  d_in[1];
    const int*   tail         = (const int*)  d_in[2];
    const float* emb_entity   = (const float*)d_in[3];
    const float* emb_relation = (const float*)d_in[4];
    const float* bias_head    = (const float*)d_in[5];
    const float* bias_tail    = (const float*)d_in[6];
    float* out = (float*)d_out;

    const int E = in_sizes[2];          // number of candidate tails (100000)

    int blocks = 2048;                  // 2048 * 4 waves = 8192 waves (full chip)
    int maxb = (E + 7) / 8;
    if (blocks > maxb) blocks = maxb;

    hipLaunchKernelGGL(transe_score_kernel, dim3(blocks), dim3(256), 0, stream,
                       head, relation, tail, emb_entity, emb_relation,
                       bias_head, bias_tail, out, E);
}

// Round 2
// 19.770 us; speedup vs baseline: 1.2720x; 1.2720x over previous
//
#include <hip/hip_runtime.h>

#define BQ  8     // batch of queries
#define DIM 128   // embedding dim

// One 32-lane group per candidate entity; lane holds float4 of 4 dims.
// 256 threads/block = 8 groups. Software-pipelined gather chain:
// tail index prefetched at depth-2, embedding row + bias at depth-1.
__global__ __launch_bounds__(256) void transe_score_kernel(
    const int*   __restrict__ head,
    const int*   __restrict__ relation,
    const int*   __restrict__ tail,
    const float* __restrict__ emb_entity,
    const float* __restrict__ emb_relation,
    const float* __restrict__ bias_head,
    const float* __restrict__ bias_tail,
    float*       __restrict__ out,
    int E)
{
    __shared__ float pred[BQ][DIM];
    __shared__ float bh_s[BQ];

    const int t = threadIdx.x;

    // pred[b][d] = emb_entity[head[b]][d] + emb_relation[relation[b]][d]
    for (int i = t; i < BQ * DIM; i += 256) {
        int b = i >> 7;       // / 128
        int d = i & 127;      // % 128
        pred[b][d] = emb_entity[(size_t)head[b] * DIM + d]
                   + emb_relation[(size_t)relation[b] * DIM + d];
    }
    if (t < BQ) bh_s[t] = bias_head[head[t]];
    __syncthreads();

    const int lane = t & 31;   // lane within 32-lane entity group
    const int grp  = t >> 5;   // entity slot within block (0..7)

    // Hoist: pm2[b] = -2 * pred fragment, pn[b] = per-lane sum of pred^2.
    // ||t-p||^2 = ||t||^2 - 2 t.p + ||p||^2  (per-lane partials, then reduce)
    float4 pm2[BQ];
    float  pn[BQ];
    float  bh[BQ];
    #pragma unroll
    for (int b = 0; b < BQ; ++b) {
        float4 p = *reinterpret_cast<const float4*>(&pred[b][lane << 2]);
        pm2[b] = make_float4(-2.f*p.x, -2.f*p.y, -2.f*p.z, -2.f*p.w);
        pn[b]  = p.x*p.x + p.y*p.y + p.z*p.z + p.w*p.w;
        bh[b]  = bh_s[b];
    }

    const int stride = gridDim.x * 8;
    int e = blockIdx.x * 8 + grp;
    if (e >= E) return;

    // ---- pipeline prologue ----
    int    te0 = tail[e];
    int    e1  = e + stride;
    int    te1 = tail[min(e1, E - 1)];           // depth-2 index (clamped dummy ok)
    float  bt0 = bias_tail[te0];
    float4 tv0 = *reinterpret_cast<const float4*>(
        &emb_entity[(size_t)te0 * DIM + (lane << 2)]);

    for (; e < E; e = e1, e1 += stride) {
        // ---- prefetch stage (independent of this iteration's compute) ----
        int    te2 = tail[min(e1 + stride, E - 1)];
        float  bt1 = bias_tail[te1];
        float4 tv1 = *reinterpret_cast<const float4*>(
            &emb_entity[(size_t)te1 * DIM + (lane << 2)]);

        // ---- compute for entity e using tv0 / bt0 ----
        float t2 = tv0.x*tv0.x + tv0.y*tv0.y + tv0.z*tv0.z + tv0.w*tv0.w;

        float acc[BQ];
        #pragma unroll
        for (int b = 0; b < BQ; ++b) {
            float a = t2 + pn[b];
            a = fmaf(tv0.x, pm2[b].x, a);
            a = fmaf(tv0.y, pm2[b].y, a);
            a = fmaf(tv0.z, pm2[b].z, a);
            a = fmaf(tv0.w, pm2[b].w, a);
            acc[b] = a;
        }

        // Selection-reduce 8 accs across 32 lanes (9 shuffles).
        {   // mask 16: 8 -> 4 accs
            bool hi = (lane & 16) != 0;
            #pragma unroll
            for (int i = 0; i < 4; ++i) {
                float send = hi ? acc[i]     : acc[i + 4];
                float keep = hi ? acc[i + 4] : acc[i];
                acc[i] = keep + __shfl_xor(send, 16, 32);
            }
        }
        {   // mask 8: 4 -> 2 accs
            bool hi = (lane & 8) != 0;
            #pragma unroll
            for (int i = 0; i < 2; ++i) {
                float send = hi ? acc[i]     : acc[i + 2];
                float keep = hi ? acc[i + 2] : acc[i];
                acc[i] = keep + __shfl_xor(send, 8, 32);
            }
        }
        {   // mask 4: 2 -> 1 acc
            bool hi = (lane & 4) != 0;
            float send = hi ? acc[0] : acc[1];
            float keep = hi ? acc[1] : acc[0];
            acc[0] = keep + __shfl_xor(send, 4, 32);
        }
        acc[0] += __shfl_xor(acc[0], 2, 32);
        acc[0] += __shfl_xor(acc[0], 1, 32);

        if ((lane & 3) == 0) {
            int b = lane >> 2;
            out[(size_t)b * E + e] = sqrtf(fmaxf(acc[0], 0.f)) + bh[b] + bt0;
        }

        // ---- rotate pipeline regs ----
        te1 = te2;
        bt0 = bt1;
        tv0 = tv1;
    }
}

extern "C" void kernel_launch(void* const* d_in, const int* in_sizes, int n_in,
                              void* d_out, int out_size, void* d_ws, size_t ws_size,
                              hipStream_t stream) {
    const int*   head         = (const int*)  d_in[0];
    const int*   relation     = (const int*)  d_in[1];
    const int*   tail         = (const int*)  d_in[2];
    const float* emb_entity   = (const float*)d_in[3];
    const float* emb_relation = (const float*)d_in[4];
    const float* bias_head    = (const float*)d_in[5];
    const float* bias_tail    = (const float*)d_in[6];
    float* out = (float*)d_out;

    const int E = in_sizes[2];          // number of candidate tails (100000)

    // 1024 blocks x 4 waves = 4096 waves = one full resident round
    // (4 waves/SIMD at <=128 VGPR); ~12 pipelined iterations per group.
    int blocks = 1024;
    int maxb = (E + 7) / 8;
    if (blocks > maxb) blocks = maxb;

    hipLaunchKernelGGL(transe_score_kernel, dim3(blocks), dim3(256), 0, stream,
                       head, relation, tail, emb_entity, emb_relation,
                       bias_head, bias_tail, out, E);
}

// Round 3
// 17.924 us; speedup vs baseline: 1.4030x; 1.1030x over previous
//
#include <hip/hip_runtime.h>

#define BQ  8     // batch of queries
#define DIM 128   // embedding dim

// One 32-lane group per PAIR of candidate entities (2p, 2p+1); lane holds a
// float4 of 4 dims. 256 threads/block = 8 groups. Depth-1 pipeline on rows
// and biases, depth-2 on tail indices -> 2 rows (1KB) in flight per group.
__global__ __launch_bounds__(256) void transe_score_kernel(
    const int*   __restrict__ head,
    const int*   __restrict__ relation,
    const int*   __restrict__ tail,
    const float* __restrict__ emb_entity,
    const float* __restrict__ emb_relation,
    const float* __restrict__ bias_head,
    const float* __restrict__ bias_tail,
    float*       __restrict__ out,
    int E)
{
    __shared__ float pred[BQ][DIM];
    __shared__ float bh_s[BQ];

    const int t = threadIdx.x;

    for (int i = t; i < BQ * DIM; i += 256) {
        int b = i >> 7, d = i & 127;
        pred[b][d] = emb_entity[(size_t)head[b] * DIM + d]
                   + emb_relation[(size_t)relation[b] * DIM + d];
    }
    if (t < BQ) bh_s[t] = bias_head[head[t]];
    __syncthreads();

    const int lane = t & 31;
    const int grp  = t >> 5;
    const int lq   = lane << 2;      // this lane's dim offset

    // ||t-p||^2 = ||t||^2 - 2 t.p + ||p||^2 ; hoist -2p and per-lane sum(p^2)
    float4 pm2[BQ];
    float  pq[BQ];
    #pragma unroll
    for (int b = 0; b < BQ; ++b) {
        float4 p = *reinterpret_cast<const float4*>(&pred[b][lq]);
        pm2[b] = make_float4(-2.f*p.x, -2.f*p.y, -2.f*p.z, -2.f*p.w);
        pq[b]  = p.x*p.x + p.y*p.y + p.z*p.z + p.w*p.w;
    }

    // Static lane->(query,entity) output mapping for the merged reduce:
    // final acc index idx=(lane>>1)&15, acc layout idx=2*b+ent.
    const int   myB   = (lane >> 2) & 7;
    const int   myEnt = (lane >> 1) & 1;
    const bool  myAct = (lane & 1) == 0;
    const float myBh  = bh_s[myB];

    const int npairs = (E + 1) >> 1;
    const int stride = gridDim.x * 8;
    int p = blockIdx.x * 8 + grp;
    if (p >= npairs) return;

    // ---- pipeline prologue ----
    int e0  = 2 * p;
    int pn1 = min(p + stride, npairs - 1);
    int na0 = tail[2 * pn1];
    int na1 = tail[min(2 * pn1 + 1, E - 1)];
    int ta0 = tail[e0];
    int ta1 = tail[min(e0 + 1, E - 1)];
    float  bt0 = bias_tail[ta0];
    float  bt1 = bias_tail[ta1];
    float4 tva = *(const float4*)&emb_entity[(size_t)ta0 * DIM + lq];
    float4 tvb = *(const float4*)&emb_entity[(size_t)ta1 * DIM + lq];

    while (p < npairs) {
        int pnext = p + stride;

        // depth-2: tail indices for p + 2*stride
        int pn2 = min(pnext + stride, npairs - 1);
        int nb0 = tail[2 * pn2];
        int nb1 = tail[min(2 * pn2 + 1, E - 1)];
        // depth-1: bias + rows for pnext (indices na0/na1 already resident)
        float  btn0 = bias_tail[na0];
        float  btn1 = bias_tail[na1];
        float4 tvna = *(const float4*)&emb_entity[(size_t)na0 * DIM + lq];
        float4 tvnb = *(const float4*)&emb_entity[(size_t)na1 * DIM + lq];

        // ---- compute pair p ----
        float t2a = tva.x*tva.x + tva.y*tva.y + tva.z*tva.z + tva.w*tva.w;
        float t2b = tvb.x*tvb.x + tvb.y*tvb.y + tvb.z*tvb.z + tvb.w*tvb.w;

        float acc[16];
        #pragma unroll
        for (int b = 0; b < BQ; ++b) {
            float a = t2a + pq[b];
            a = fmaf(tva.x, pm2[b].x, a);
            a = fmaf(tva.y, pm2[b].y, a);
            a = fmaf(tva.z, pm2[b].z, a);
            a = fmaf(tva.w, pm2[b].w, a);
            acc[2*b] = a;
            float c = t2b + pq[b];
            c = fmaf(tvb.x, pm2[b].x, c);
            c = fmaf(tvb.y, pm2[b].y, c);
            c = fmaf(tvb.z, pm2[b].z, c);
            c = fmaf(tvb.w, pm2[b].w, c);
            acc[2*b+1] = c;
        }

        // ---- merged selection-reduce: 16 accs over 32 lanes, 16 shuffles ----
        {   bool hi = (lane & 16) != 0;
            #pragma unroll
            for (int i = 0; i < 8; ++i) {
                float send = hi ? acc[i]     : acc[i + 8];
                float keep = hi ? acc[i + 8] : acc[i];
                acc[i] = keep + __shfl_xor(send, 16, 32);
            } }
        {   bool hi = (lane & 8) != 0;
            #pragma unroll
            for (int i = 0; i < 4; ++i) {
                float send = hi ? acc[i]     : acc[i + 4];
                float keep = hi ? acc[i + 4] : acc[i];
                acc[i] = keep + __shfl_xor(send, 8, 32);
            } }
        {   bool hi = (lane & 4) != 0;
            #pragma unroll
            for (int i = 0; i < 2; ++i) {
                float send = hi ? acc[i]     : acc[i + 2];
                float keep = hi ? acc[i + 2] : acc[i];
                acc[i] = keep + __shfl_xor(send, 4, 32);
            } }
        {   bool hi = (lane & 2) != 0;
            float send = hi ? acc[0] : acc[1];
            float keep = hi ? acc[1] : acc[0];
            acc[0] = keep + __shfl_xor(send, 2, 32);
        }
        acc[0] += __shfl_xor(acc[0], 1, 32);

        if (myAct) {
            int eo = e0 + myEnt;
            if (eo < E) {
                float bt = myEnt ? bt1 : bt0;
                out[(size_t)myB * E + eo] = sqrtf(fmaxf(acc[0], 0.f)) + myBh + bt;
            }
        }

        // ---- rotate pipeline ----
        p = pnext; e0 = 2 * p;
        na0 = nb0;  na1 = nb1;
        bt0 = btn0; bt1 = btn1;
        tva = tvna; tvb = tvnb;
    }
}

extern "C" void kernel_launch(void* const* d_in, const int* in_sizes, int n_in,
                              void* d_out, int out_size, void* d_ws, size_t ws_size,
                              hipStream_t stream) {
    const int*   head         = (const int*)  d_in[0];
    const int*   relation     = (const int*)  d_in[1];
    const int*   tail         = (const int*)  d_in[2];
    const float* emb_entity   = (const float*)d_in[3];
    const float* emb_relation = (const float*)d_in[4];
    const float* bias_head    = (const float*)d_in[5];
    const float* bias_tail    = (const float*)d_in[6];
    float* out = (float*)d_out;

    const int E = in_sizes[2];
    const int npairs = (E + 1) >> 1;

    // 1024 blocks x 4 waves = 4096 waves = one resident round at ~100 VGPR.
    int blocks = 1024;
    int maxb = (npairs + 7) / 8;
    if (blocks > maxb) blocks = maxb;

    hipLaunchKernelGGL(transe_score_kernel, dim3(blocks), dim3(256), 0, stream,
                       head, relation, tail, emb_entity, emb_relation,
                       bias_head, bias_tail, out, E);
}